// Round 5
// baseline (404.055 us; speedup 1.0000x reference)
//
#include <hip/hip_runtime.h>
#include <hip/hip_bf16.h>
#include <stdint.h>

#define NB 4096
#define NCOL 100
#define NCOND 64
#define NTOTAL 6400
#define NRODT 1600
#define NEST 160
#define NFOR 100
#define NHID 128
#define NCLS 10
#define GEPS 1e-5f

typedef __attribute__((ext_vector_type(8))) short short8;
typedef __attribute__((ext_vector_type(4))) float floatx4;

__device__ __forceinline__ unsigned short f2bf(float x) {
  union { float f; unsigned u; } v; v.f = x;
  unsigned r = v.u + 0x7fffu + ((v.u >> 16) & 1u);   // RNE
  return (unsigned short)(r >> 16);
}

// ---------------------------------------------------------------------------
// K1: fused ConditionGeneration + perm + phi_2 -> w logits [b][g] f32.
// grid (NB/8, 4): 8 samples x 400-group chunk per block = 2048 blocks.
// ---------------------------------------------------------------------------
__global__ __launch_bounds__(256) void k1_w(
    const float* __restrict__ x, const float* __restrict__ w1,
    const float* __restrict__ b1, const int* __restrict__ perm,
    const float* __restrict__ gn1w, const float* __restrict__ gn1b,
    const float* __restrict__ c2w, const float* __restrict__ c2b,
    const float* __restrict__ gn2w, const float* __restrict__ gn2b,
    const float* __restrict__ c3w, const float* __restrict__ c3b,
    float* __restrict__ wout)
{
  __shared__ float xl[8 * NCOL];
  const int b0 = blockIdx.x * 8;
  const int g0 = blockIdx.y * 400;
  for (int i = threadIdx.x; i < 8 * NCOL; i += 256)
    xl[i] = x[(size_t)b0 * NCOL + i];
  __syncthreads();

  for (int g = g0 + threadIdx.x; g < g0 + 400; g += 256) {
    const int4 p4 = *(const int4*)(perm + 4 * g);
    const int pv[4] = {p4.x, p4.y, p4.z, p4.w};
    float w1v[4], b1v[4];
    int pc[4];
#pragma unroll
    for (int i = 0; i < 4; i++) {
      unsigned p = (unsigned)pv[i];
      unsigned j = p / 100u;
      unsigned cc = p - j * 100u;
      pc[i] = (int)cc;
      w1v[i] = w1[cc * NCOND + j];
      b1v[i] = b1[cc * NCOND + j];
    }
    const float4 g1w = *(const float4*)(gn1w + 4 * g);
    const float4 g1b = *(const float4*)(gn1b + 4 * g);
    const float4 cw0 = *(const float4*)(c2w + 16 * g);
    const float4 cw1 = *(const float4*)(c2w + 16 * g + 4);
    const float4 cw2 = *(const float4*)(c2w + 16 * g + 8);
    const float4 cw3 = *(const float4*)(c2w + 16 * g + 12);
    const float4 cbv = *(const float4*)(c2b + 4 * g);
    const float4 g2w = *(const float4*)(gn2w + 4 * g);
    const float4 g2b = *(const float4*)(gn2b + 4 * g);
    const float4 c3v = *(const float4*)(c3w + 4 * g);
    const float c3bv = c3b[g];

    for (int bb = 0; bb < 8; bb++) {
      float O[4];
#pragma unroll
      for (int i = 0; i < 4; i++) {
        float a = xl[bb * NCOL + pc[i]] * w1v[i] + b1v[i];
        O[i] = 1.0f / (1.0f + __expf(-a));
      }
      float mu = 0.25f * (O[0] + O[1] + O[2] + O[3]);
      float d[4], var = 0.f;
#pragma unroll
      for (int i = 0; i < 4; i++) { d[i] = O[i] - mu; var += d[i] * d[i]; }
      float rs = rsqrtf(0.25f * var + GEPS);
      float xn0 = d[0] * rs * g1w.x + g1b.x;
      float xn1 = d[1] * rs * g1w.y + g1b.y;
      float xn2 = d[2] * rs * g1w.z + g1b.z;
      float xn3 = d[3] * rs * g1w.w + g1b.w;
      float h[4];
      h[0] = xn0*cw0.x + xn1*cw1.x + xn2*cw2.x + xn3*cw3.x + cbv.x;
      h[1] = xn0*cw0.y + xn1*cw1.y + xn2*cw2.y + xn3*cw3.y + cbv.y;
      h[2] = xn0*cw0.z + xn1*cw1.z + xn2*cw2.z + xn3*cw3.z + cbv.z;
      h[3] = xn0*cw0.w + xn1*cw1.w + xn2*cw2.w + xn3*cw3.w + cbv.w;
#pragma unroll
      for (int i = 0; i < 4; i++) h[i] = fmaxf(h[i], 0.f);
      float mu2 = 0.25f * (h[0] + h[1] + h[2] + h[3]);
      float e[4], var2 = 0.f;
#pragma unroll
      for (int i = 0; i < 4; i++) { e[i] = h[i] - mu2; var2 += e[i] * e[i]; }
      float rs2 = rsqrtf(0.25f * var2 + GEPS);
      float hn0 = e[0] * rs2 * g2w.x + g2b.x;
      float hn1 = e[1] * rs2 * g2w.y + g2b.y;
      float hn2 = e[2] * rs2 * g2w.z + g2b.z;
      float hn3 = e[3] * rs2 * g2w.w + g2b.w;
      float wv = hn0*c3v.x + hn1*c3v.y + hn2*c3v.z + hn3*c3v.w + c3bv;
      wout[(size_t)(b0 + bb) * NRODT + g] = wv;
    }
  }
}

// ---------------------------------------------------------------------------
// K0: fragment-pack B operands.
//  blocks 0..99 : Bf[f][n=8][kc=5][lane=64][8]  = E[swr[f][kc*32+q*8+j]][n*16+c]
//  block  100   : W1f[n=8][kc=4][lane][8]       = fc1w[kc*32+q*8+j][n*16+c]
//  block  101   : W2f[kc=4][lane][8]            = c<10 ? fc2w[k][c] : 0
//  (lane = q*16+c) -> k3's B loads are base + lane*16, fully coalesced.
// ---------------------------------------------------------------------------
__global__ __launch_bounds__(256) void k0_prep(
    const float* __restrict__ E, const int* __restrict__ swr,
    const float* __restrict__ fc1w, const float* __restrict__ fc2w,
    unsigned short* __restrict__ Bf, unsigned short* __restrict__ W1f,
    unsigned short* __restrict__ W2f)
{
  __shared__ int ridx[NEST];
  const int tid = threadIdx.x;
  const int blk = blockIdx.x;

  if (blk < NFOR) {
    if (tid < NEST) ridx[tid] = swr[blk * NEST + tid];
    __syncthreads();
    for (int m = tid; m < 2560; m += 256) {        // m = (n*5+kc)*64 + lane
      int lane = m & 63, rest = m >> 6;
      int kc = rest % 5, n = rest / 5;
      int q = lane >> 4, c = lane & 15;
      int e0 = kc * 32 + q * 8;
      int h = n * 16 + c;
      union { unsigned short v[8]; uint4 u; } t;
#pragma unroll
      for (int j = 0; j < 8; j++)
        t.v[j] = f2bf(E[(size_t)ridx[e0 + j] * NHID + h]);
      *(uint4*)(Bf + (size_t)blk * 20480 + (size_t)m * 8) = t.u;
    }
  } else if (blk == NFOR) {
    for (int m = tid; m < 2048; m += 256) {        // m = (n*4+kc)*64 + lane
      int lane = m & 63, rest = m >> 6;
      int kc = rest & 3, n = rest >> 2;
      int q = lane >> 4, c = lane & 15;
      int k0 = kc * 32 + q * 8;
      int o = n * 16 + c;
      union { unsigned short v[8]; uint4 u; } t;
#pragma unroll
      for (int j = 0; j < 8; j++)
        t.v[j] = f2bf(fc1w[(size_t)(k0 + j) * NHID + o]);
      *(uint4*)(W1f + (size_t)m * 8) = t.u;
    }
  } else {
    for (int m = tid; m < 256; m += 256) {         // m = kc*64 + lane
      int lane = m & 63, kc = m >> 6;
      int q = lane >> 4, c = lane & 15;
      int k0 = kc * 32 + q * 8;
      union { unsigned short v[8]; uint4 u; } t;
#pragma unroll
      for (int j = 0; j < 8; j++)
        t.v[j] = f2bf(c < NCLS ? fc2w[(size_t)(k0 + j) * NCLS + c] : 0.f);
      *(uint4*)(W2f + (size_t)m * 8) = t.u;
    }
  }
}

// ---------------------------------------------------------------------------
// K3: gather + softmax + MFMA pipeline, fully fused.
// A-frag for GEMM1 built in-register: each lane gathers its 40 logits
// w[row=c][k=ridx[kc*32+q*8+j]]; softmax row-reduce = shfl_xor(16,32) over
// the 4 lanes (q) co-owning the row; exp+scale -> bf16 frags.
// ---------------------------------------------------------------------------
__global__ __launch_bounds__(256, 4) void k3_mfma(
    const float* __restrict__ wlog,           // [B][1600] f32 logits
    const int* __restrict__ swr,
    const unsigned short* __restrict__ Bf,    // [f][8][5][64][8]
    const unsigned short* __restrict__ W1f,   // [8][4][64][8]
    const unsigned short* __restrict__ W2f,   // [4][64][8]
    const float* __restrict__ ln1w, const float* __restrict__ ln1b,
    const float* __restrict__ fc1b,
    const float* __restrict__ ln2w, const float* __restrict__ ln2b,
    const float* __restrict__ fc2b,
    float* __restrict__ out)
{
  __shared__ unsigned short lsA[64 * 168];    // 21504 B
  __shared__ int ridx[NEST];

  const int tid = threadIdx.x;
  const int b0 = blockIdx.x * 64;
  const int f  = blockIdx.y;
  const int lane = tid & 63, wv = tid >> 6;
  const int c = lane & 15, q = lane >> 4;

  if (tid < NEST) ridx[tid] = swr[f * NEST + tid];
  __syncthreads();

  // ---- gather 40 logits for this lane's A-fragment slots ----
  const float* wrow = wlog + (size_t)(b0 + wv * 16 + c) * NRODT;
  float g[40];
#pragma unroll
  for (int kc = 0; kc < 5; kc++)
#pragma unroll
    for (int j = 0; j < 8; j++)
      g[kc * 8 + j] = wrow[ridx[kc * 32 + q * 8 + j]];

  // ---- softmax over the row (4 lanes x 40 values) ----
  float mx = -1e30f;
#pragma unroll
  for (int i = 0; i < 40; i++) mx = fmaxf(mx, g[i]);
  mx = fmaxf(mx, __shfl_xor(mx, 16));
  mx = fmaxf(mx, __shfl_xor(mx, 32));
  float s = 0.f;
#pragma unroll
  for (int i = 0; i < 40; i++) { g[i] = __expf(g[i] - mx); s += g[i]; }
  s += __shfl_xor(s, 16);
  s += __shfl_xor(s, 32);
  const float inv = 1.0f / s;

  union { unsigned short v[8]; short8 s8; } ap[5];
#pragma unroll
  for (int kc = 0; kc < 5; kc++)
#pragma unroll
    for (int j = 0; j < 8; j++)
      ap[kc].v[j] = f2bf(g[kc * 8 + j] * inv);

  // ---- GEMM1: F = ws[64x160] @ Ep[160x128] ----
  floatx4 acc[8];
#pragma unroll
  for (int n = 0; n < 8; n++) acc[n] = (floatx4){0.f, 0.f, 0.f, 0.f};

  const unsigned short* bbase = Bf + (size_t)f * 20480 + lane * 8;
#pragma unroll
  for (int n = 0; n < 8; n++) {
    const unsigned short* bp = bbase + n * 2560;
#pragma unroll
    for (int kc = 0; kc < 5; kc++) {
      short8 b = *(const short8*)(bp + kc * 512);
      acc[n] = __builtin_amdgcn_mfma_f32_16x16x32_bf16(ap[kc].s8, b, acc[n], 0, 0, 0);
    }
  }

  // ---- LN1 (C-layout: row=q*4+r, col=16n+c; reduce over 16 lanes) ----
  {
    float lw[8], lb[8];
#pragma unroll
    for (int n = 0; n < 8; n++) { lw[n] = ln1w[n * 16 + c]; lb[n] = ln1b[n * 16 + c]; }
#pragma unroll
    for (int r = 0; r < 4; r++) {
      float s1 = 0.f, s2 = 0.f;
#pragma unroll
      for (int n = 0; n < 8; n++) { float v = acc[n][r]; s1 += v; s2 += v * v; }
#pragma unroll
      for (int off = 1; off < 16; off <<= 1) {
        s1 += __shfl_xor(s1, off); s2 += __shfl_xor(s2, off);
      }
      float mu = s1 * (1.f / 128.f);
      float var = fmaxf(s2 * (1.f / 128.f) - mu * mu, 0.f);
      float rs = rsqrtf(var + GEPS);
#pragma unroll
      for (int n = 0; n < 8; n++)
        acc[n][r] = (acc[n][r] - mu) * rs * lw[n] + lb[n];
    }
  }

  // ---- Fn -> lsA (A-layout bf16, wave-private strip) ----
#pragma unroll
  for (int r = 0; r < 4; r++)
#pragma unroll
    for (int n = 0; n < 8; n++)
      lsA[(wv * 16 + q * 4 + r) * 168 + n * 16 + c] = f2bf(acc[n][r]);
  __syncthreads();

  // ---- GEMM2: H = Fn[64x128] @ fc1w[128x128] ----
  const unsigned short* pa = lsA + (wv * 16 + c) * 168 + q * 8;
  short8 a2[4];
#pragma unroll
  for (int kc = 0; kc < 4; kc++) a2[kc] = *(const short8*)(pa + kc * 32);
#pragma unroll
  for (int n = 0; n < 8; n++) acc[n] = (floatx4){0.f, 0.f, 0.f, 0.f};
  const unsigned short* w1p = W1f + lane * 8;
#pragma unroll
  for (int n = 0; n < 8; n++) {
#pragma unroll
    for (int kc = 0; kc < 4; kc++) {
      short8 b = *(const short8*)(w1p + (n * 4 + kc) * 512);
      acc[n] = __builtin_amdgcn_mfma_f32_16x16x32_bf16(a2[kc], b, acc[n], 0, 0, 0);
    }
  }

  // ---- bias + ReLU + LN2 ----
  {
    float fb[8], lw[8], lb[8];
#pragma unroll
    for (int n = 0; n < 8; n++) {
      fb[n] = fc1b[n * 16 + c];
      lw[n] = ln2w[n * 16 + c]; lb[n] = ln2b[n * 16 + c];
    }
#pragma unroll
    for (int r = 0; r < 4; r++) {
#pragma unroll
      for (int n = 0; n < 8; n++) acc[n][r] = fmaxf(acc[n][r] + fb[n], 0.f);
      float s1 = 0.f, s2 = 0.f;
#pragma unroll
      for (int n = 0; n < 8; n++) { float v = acc[n][r]; s1 += v; s2 += v * v; }
#pragma unroll
      for (int off = 1; off < 16; off <<= 1) {
        s1 += __shfl_xor(s1, off); s2 += __shfl_xor(s2, off);
      }
      float mu = s1 * (1.f / 128.f);
      float var = fmaxf(s2 * (1.f / 128.f) - mu * mu, 0.f);
      float rs = rsqrtf(var + GEPS);
#pragma unroll
      for (int n = 0; n < 8; n++)
        acc[n][r] = (acc[n][r] - mu) * rs * lw[n] + lb[n];
    }
  }
  __syncthreads();   // all GEMM2 frag reads done before overwrite

  // ---- H2 -> lsA (A-layout) ----
#pragma unroll
  for (int r = 0; r < 4; r++)
#pragma unroll
    for (int n = 0; n < 8; n++)
      lsA[(wv * 16 + q * 4 + r) * 168 + n * 16 + c] = f2bf(acc[n][r]);
  __syncthreads();

  // ---- fc2 (16-col padded tile) + mean-atomic ----
  short8 a3[4];
#pragma unroll
  for (int kc = 0; kc < 4; kc++) a3[kc] = *(const short8*)(pa + kc * 32);
  floatx4 o4 = (floatx4){0.f, 0.f, 0.f, 0.f};
#pragma unroll
  for (int kc = 0; kc < 4; kc++) {
    short8 b = *(const short8*)(W2f + kc * 512 + lane * 8);
    o4 = __builtin_amdgcn_mfma_f32_16x16x32_bf16(a3[kc], b, o4, 0, 0, 0);
  }
  if (c < NCLS) {
    float bias = fc2b[c];
#pragma unroll
    for (int r = 0; r < 4; r++)
      atomicAdd(out + (size_t)(b0 + wv * 16 + q * 4 + r) * NCLS + c,
                (o4[r] + bias) * 0.01f);
  }
}

// ---------------------------------------------------------------------------
extern "C" void kernel_launch(void* const* d_in, const int* in_sizes, int n_in,
                              void* d_out, int out_size, void* d_ws, size_t ws_size,
                              hipStream_t stream)
{
  (void)in_sizes; (void)n_in; (void)ws_size;
  const float* x    = (const float*)d_in[0];
  const float* w1   = (const float*)d_in[1];
  const float* b1   = (const float*)d_in[2];
  const int*   perm = (const int*)d_in[3];
  const float* gn1w = (const float*)d_in[4];
  const float* gn1b = (const float*)d_in[5];
  const float* c2w  = (const float*)d_in[6];
  const float* c2b  = (const float*)d_in[7];
  const float* gn2w = (const float*)d_in[8];
  const float* gn2b = (const float*)d_in[9];
  const float* c3w  = (const float*)d_in[10];
  const float* c3b  = (const float*)d_in[11];
  const int*   swr  = (const int*)d_in[12];
  const float* E    = (const float*)d_in[13];
  const float* ln1w = (const float*)d_in[14];
  const float* ln1b = (const float*)d_in[15];
  const float* fc1w = (const float*)d_in[16];
  const float* fc1b = (const float*)d_in[17];
  const float* ln2w = (const float*)d_in[18];
  const float* ln2b = (const float*)d_in[19];
  const float* fc2w = (const float*)d_in[20];
  const float* fc2b = (const float*)d_in[21];
  float* out = (float*)d_out;

  // workspace layout (w persists through k3 now; k0 outputs live AFTER it):
  //   [0, 26.2MB)           : w logits f32 [B][1600]
  //   [26.2MB, +4.10MB)     : Bf  (100*20480 shorts = 4,096,000 B)
  //   then W1f 32,768 B, W2f 4,096 B
  const size_t W_BYTES = (size_t)NB * NRODT * 4;     // 26,214,400
  float* wbuf = (float*)d_ws;
  unsigned short* Bfb   = (unsigned short*)((char*)d_ws + W_BYTES);
  unsigned short* W1fb  = (unsigned short*)((char*)d_ws + W_BYTES + 4096000);
  unsigned short* W2fb  = (unsigned short*)((char*)d_ws + W_BYTES + 4096000 + 32768);

  hipMemsetAsync(d_out, 0, (size_t)out_size * sizeof(float), stream);
  dim3 g1(NB / 8, 4);
  k1_w<<<g1, 256, 0, stream>>>(x, w1, b1, perm, gn1w, gn1b, c2w, c2b,
                               gn2w, gn2b, c3w, c3b, wbuf);
  k0_prep<<<NFOR + 2, 256, 0, stream>>>(E, swr, fc1w, fc2w, Bfb, W1fb, W2fb);
  dim3 g3(NB / 64, NFOR);
  k3_mfma<<<g3, 256, 0, stream>>>(wbuf, swr, Bfb, W1fb, W2fb,
                                  ln1w, ln1b, fc1b, ln2w, ln2b, fc2b, out);
}

// Round 6
// 274.633 us; speedup vs baseline: 1.4713x; 1.4713x over previous
//
#include <hip/hip_runtime.h>
#include <hip/hip_bf16.h>
#include <stdint.h>

#define NB 4096
#define NCOL 100
#define NCOND 64
#define NTOTAL 6400
#define NRODT 1600
#define NEST 160
#define NFOR 100
#define NHID 128
#define NCLS 10
#define GEPS 1e-5f

typedef __attribute__((ext_vector_type(8))) short short8;
typedef __attribute__((ext_vector_type(4))) float floatx4;

__device__ __forceinline__ unsigned short f2bf(float x) {
  union { float f; unsigned u; } v; v.f = x;
  unsigned r = v.u + 0x7fffu + ((v.u >> 16) & 1u);   // RNE
  return (unsigned short)(r >> 16);
}

// ---------------------------------------------------------------------------
// K1: fused ConditionGeneration + perm + phi_2 -> TRANSPOSED logits wT[g][b].
// grid (NB/8, 4): 8 samples x 400-group chunk per block.  Each thread owns a
// g-row and writes its 8 b's as two float4s (contiguous in b).
// ---------------------------------------------------------------------------
__global__ __launch_bounds__(256) void k1_w(
    const float* __restrict__ x, const float* __restrict__ w1,
    const float* __restrict__ b1, const int* __restrict__ perm,
    const float* __restrict__ gn1w, const float* __restrict__ gn1b,
    const float* __restrict__ c2w, const float* __restrict__ c2b,
    const float* __restrict__ gn2w, const float* __restrict__ gn2b,
    const float* __restrict__ c3w, const float* __restrict__ c3b,
    float* __restrict__ wT)
{
  __shared__ float xl[8 * NCOL];
  const int b0 = blockIdx.x * 8;
  const int g0 = blockIdx.y * 400;
  for (int i = threadIdx.x; i < 8 * NCOL; i += 256)
    xl[i] = x[(size_t)b0 * NCOL + i];
  __syncthreads();

  for (int g = g0 + threadIdx.x; g < g0 + 400; g += 256) {
    const int4 p4 = *(const int4*)(perm + 4 * g);
    const int pv[4] = {p4.x, p4.y, p4.z, p4.w};
    float w1v[4], b1v[4];
    int pc[4];
#pragma unroll
    for (int i = 0; i < 4; i++) {
      unsigned p = (unsigned)pv[i];
      unsigned j = p / 100u;
      unsigned cc = p - j * 100u;
      pc[i] = (int)cc;
      w1v[i] = w1[cc * NCOND + j];
      b1v[i] = b1[cc * NCOND + j];
    }
    const float4 g1w = *(const float4*)(gn1w + 4 * g);
    const float4 g1b = *(const float4*)(gn1b + 4 * g);
    const float4 cw0 = *(const float4*)(c2w + 16 * g);
    const float4 cw1 = *(const float4*)(c2w + 16 * g + 4);
    const float4 cw2 = *(const float4*)(c2w + 16 * g + 8);
    const float4 cw3 = *(const float4*)(c2w + 16 * g + 12);
    const float4 cbv = *(const float4*)(c2b + 4 * g);
    const float4 g2w = *(const float4*)(gn2w + 4 * g);
    const float4 g2b = *(const float4*)(gn2b + 4 * g);
    const float4 c3v = *(const float4*)(c3w + 4 * g);
    const float c3bv = c3b[g];

    float wv8[8];
    for (int bb = 0; bb < 8; bb++) {
      float O[4];
#pragma unroll
      for (int i = 0; i < 4; i++) {
        float a = xl[bb * NCOL + pc[i]] * w1v[i] + b1v[i];
        O[i] = 1.0f / (1.0f + __expf(-a));
      }
      float mu = 0.25f * (O[0] + O[1] + O[2] + O[3]);
      float d[4], var = 0.f;
#pragma unroll
      for (int i = 0; i < 4; i++) { d[i] = O[i] - mu; var += d[i] * d[i]; }
      float rs = rsqrtf(0.25f * var + GEPS);
      float xn0 = d[0] * rs * g1w.x + g1b.x;
      float xn1 = d[1] * rs * g1w.y + g1b.y;
      float xn2 = d[2] * rs * g1w.z + g1b.z;
      float xn3 = d[3] * rs * g1w.w + g1b.w;
      float h[4];
      h[0] = xn0*cw0.x + xn1*cw1.x + xn2*cw2.x + xn3*cw3.x + cbv.x;
      h[1] = xn0*cw0.y + xn1*cw1.y + xn2*cw2.y + xn3*cw3.y + cbv.y;
      h[2] = xn0*cw0.z + xn1*cw1.z + xn2*cw2.z + xn3*cw3.z + cbv.z;
      h[3] = xn0*cw0.w + xn1*cw1.w + xn2*cw2.w + xn3*cw3.w + cbv.w;
#pragma unroll
      for (int i = 0; i < 4; i++) h[i] = fmaxf(h[i], 0.f);
      float mu2 = 0.25f * (h[0] + h[1] + h[2] + h[3]);
      float e[4], var2 = 0.f;
#pragma unroll
      for (int i = 0; i < 4; i++) { e[i] = h[i] - mu2; var2 += e[i] * e[i]; }
      float rs2 = rsqrtf(0.25f * var2 + GEPS);
      float hn0 = e[0] * rs2 * g2w.x + g2b.x;
      float hn1 = e[1] * rs2 * g2w.y + g2b.y;
      float hn2 = e[2] * rs2 * g2w.z + g2b.z;
      float hn3 = e[3] * rs2 * g2w.w + g2b.w;
      wv8[bb] = hn0*c3v.x + hn1*c3v.y + hn2*c3v.z + hn3*c3v.w + c3bv;
    }
    float* o = wT + (size_t)g * NB + b0;
    *(float4*)o       = make_float4(wv8[0], wv8[1], wv8[2], wv8[3]);
    *(float4*)(o + 4) = make_float4(wv8[4], wv8[5], wv8[6], wv8[7]);
  }
}

// ---------------------------------------------------------------------------
// K0: fragment-pack B operands.
//  blocks 0..99 : Bf[f][n=8][kc=5][lane=64][8]  = E[swr[f][kc*32+q*8+j]][n*16+c]
//  block  100   : W1f[n=8][kc=4][lane][8]       = fc1w[kc*32+q*8+j][n*16+c]
//  block  101   : W2f[kc=4][lane][8]            = c<10 ? fc2w[k][c] : 0
// ---------------------------------------------------------------------------
__global__ __launch_bounds__(256) void k0_prep(
    const float* __restrict__ E, const int* __restrict__ swr,
    const float* __restrict__ fc1w, const float* __restrict__ fc2w,
    unsigned short* __restrict__ Bf, unsigned short* __restrict__ W1f,
    unsigned short* __restrict__ W2f)
{
  __shared__ int ridx[NEST];
  const int tid = threadIdx.x;
  const int blk = blockIdx.x;

  if (blk < NFOR) {
    if (tid < NEST) ridx[tid] = swr[blk * NEST + tid];
    __syncthreads();
    for (int m = tid; m < 2560; m += 256) {        // m = (n*5+kc)*64 + lane
      int lane = m & 63, rest = m >> 6;
      int kc = rest % 5, n = rest / 5;
      int q = lane >> 4, c = lane & 15;
      int e0 = kc * 32 + q * 8;
      int h = n * 16 + c;
      union { unsigned short v[8]; uint4 u; } t;
#pragma unroll
      for (int j = 0; j < 8; j++)
        t.v[j] = f2bf(E[(size_t)ridx[e0 + j] * NHID + h]);
      *(uint4*)(Bf + (size_t)blk * 20480 + (size_t)m * 8) = t.u;
    }
  } else if (blk == NFOR) {
    for (int m = tid; m < 2048; m += 256) {        // m = (n*4+kc)*64 + lane
      int lane = m & 63, rest = m >> 6;
      int kc = rest & 3, n = rest >> 2;
      int q = lane >> 4, c = lane & 15;
      int k0 = kc * 32 + q * 8;
      int o = n * 16 + c;
      union { unsigned short v[8]; uint4 u; } t;
#pragma unroll
      for (int j = 0; j < 8; j++)
        t.v[j] = f2bf(fc1w[(size_t)(k0 + j) * NHID + o]);
      *(uint4*)(W1f + (size_t)m * 8) = t.u;
    }
  } else {
    for (int m = tid; m < 256; m += 256) {         // m = kc*64 + lane
      int lane = m & 63, kc = m >> 6;
      int q = lane >> 4, c = lane & 15;
      int k0 = kc * 32 + q * 8;
      union { unsigned short v[8]; uint4 u; } t;
#pragma unroll
      for (int j = 0; j < 8; j++)
        t.v[j] = f2bf(c < NCLS ? fc2w[(size_t)(k0 + j) * NCLS + c] : 0.f);
      *(uint4*)(W2f + (size_t)m * 8) = t.u;
    }
  }
}

// ---------------------------------------------------------------------------
// K3: staged-gather + softmax + MFMA pipeline.
// Stage: G[e][r] = wT[ridx[e]][b0+r]  -- lane-consecutive r => fully
// coalesced global loads AND conflict-free LDS writes.  Gather+softmax from
// LDS (2 lanes/bank = free), pack A-frags in-register, then the R4 MFMA
// pipeline.  G (f32, stride 66) overlays lsA (bf16, stride 168).
// ---------------------------------------------------------------------------
__global__ __launch_bounds__(256, 3) void k3_mfma(
    const float* __restrict__ wT,             // [1600][B] f32 logits^T
    const int* __restrict__ swr,
    const unsigned short* __restrict__ Bf,    // [f][8][5][64][8]
    const unsigned short* __restrict__ W1f,   // [8][4][64][8]
    const unsigned short* __restrict__ W2f,   // [4][64][8]
    const float* __restrict__ ln1w, const float* __restrict__ ln1b,
    const float* __restrict__ fc1b,
    const float* __restrict__ ln2w, const float* __restrict__ ln2b,
    const float* __restrict__ fc2b,
    float* __restrict__ out)
{
  __shared__ __align__(16) char lsraw[NEST * 66 * 4];   // 42,240 B
  float* G = (float*)lsraw;                    // [e][66] logits tile
  unsigned short* lsA = (unsigned short*)lsraw; // later: [64][168] bf16 A-tile
  __shared__ int ridx[NEST];

  const int tid = threadIdx.x;
  const int b0 = blockIdx.x * 64;
  const int f  = blockIdx.y;
  const int lane = tid & 63, wv = tid >> 6;
  const int c = lane & 15, q = lane >> 4;

  if (tid < NEST) ridx[tid] = swr[f * NEST + tid];
  __syncthreads();

  // ---- stage gathered logits tile (coalesced: lane-consecutive r) ----
  for (int i = tid; i < NEST * 64; i += 256) {
    int e = i >> 6, r = i & 63;
    G[e * 66 + r] = wT[(size_t)ridx[e] * NB + b0 + r];
  }
  __syncthreads();

  // ---- per-lane gather from LDS + softmax over row (4 lanes x 40) ----
  const int row = wv * 16 + c;
  float g[40];
#pragma unroll
  for (int kc = 0; kc < 5; kc++)
#pragma unroll
    for (int j = 0; j < 8; j++)
      g[kc * 8 + j] = G[(kc * 32 + q * 8 + j) * 66 + row];

  float mx = -1e30f;
#pragma unroll
  for (int i = 0; i < 40; i++) mx = fmaxf(mx, g[i]);
  mx = fmaxf(mx, __shfl_xor(mx, 16));
  mx = fmaxf(mx, __shfl_xor(mx, 32));
  float s = 0.f;
#pragma unroll
  for (int i = 0; i < 40; i++) { g[i] = __expf(g[i] - mx); s += g[i]; }
  s += __shfl_xor(s, 16);
  s += __shfl_xor(s, 32);
  const float inv = 1.0f / s;

  union { unsigned short v[8]; short8 s8; } ap[5];
#pragma unroll
  for (int kc = 0; kc < 5; kc++)
#pragma unroll
    for (int j = 0; j < 8; j++)
      ap[kc].v[j] = f2bf(g[kc * 8 + j] * inv);
  __syncthreads();   // all waves done reading G before lsA overlay is written

  // ---- GEMM1: F = ws[64x160] @ Ep[160x128] ----
  floatx4 acc[8];
#pragma unroll
  for (int n = 0; n < 8; n++) acc[n] = (floatx4){0.f, 0.f, 0.f, 0.f};

  const unsigned short* bbase = Bf + (size_t)f * 20480 + lane * 8;
#pragma unroll
  for (int n = 0; n < 8; n++) {
    const unsigned short* bp = bbase + n * 2560;
#pragma unroll
    for (int kc = 0; kc < 5; kc++) {
      short8 b = *(const short8*)(bp + kc * 512);
      acc[n] = __builtin_amdgcn_mfma_f32_16x16x32_bf16(ap[kc].s8, b, acc[n], 0, 0, 0);
    }
  }

  // ---- LN1 (C-layout: row=q*4+r, col=16n+c; reduce over 16 lanes) ----
  {
    float lw[8], lb[8];
#pragma unroll
    for (int n = 0; n < 8; n++) { lw[n] = ln1w[n * 16 + c]; lb[n] = ln1b[n * 16 + c]; }
#pragma unroll
    for (int r = 0; r < 4; r++) {
      float s1 = 0.f, s2 = 0.f;
#pragma unroll
      for (int n = 0; n < 8; n++) { float v = acc[n][r]; s1 += v; s2 += v * v; }
#pragma unroll
      for (int off = 1; off < 16; off <<= 1) {
        s1 += __shfl_xor(s1, off); s2 += __shfl_xor(s2, off);
      }
      float mu = s1 * (1.f / 128.f);
      float var = fmaxf(s2 * (1.f / 128.f) - mu * mu, 0.f);
      float rs = rsqrtf(var + GEPS);
#pragma unroll
      for (int n = 0; n < 8; n++)
        acc[n][r] = (acc[n][r] - mu) * rs * lw[n] + lb[n];
    }
  }

  // ---- Fn -> lsA (A-layout bf16, wave-private strip) ----
#pragma unroll
  for (int r = 0; r < 4; r++)
#pragma unroll
    for (int n = 0; n < 8; n++)
      lsA[(wv * 16 + q * 4 + r) * 168 + n * 16 + c] = f2bf(acc[n][r]);
  __syncthreads();

  // ---- GEMM2: H = Fn[64x128] @ fc1w[128x128] ----
  const unsigned short* pa = lsA + (wv * 16 + c) * 168 + q * 8;
  short8 a2[4];
#pragma unroll
  for (int kc = 0; kc < 4; kc++) a2[kc] = *(const short8*)(pa + kc * 32);
#pragma unroll
  for (int n = 0; n < 8; n++) acc[n] = (floatx4){0.f, 0.f, 0.f, 0.f};
  const unsigned short* w1p = W1f + lane * 8;
#pragma unroll
  for (int n = 0; n < 8; n++) {
#pragma unroll
    for (int kc = 0; kc < 4; kc++) {
      short8 b = *(const short8*)(w1p + (n * 4 + kc) * 512);
      acc[n] = __builtin_amdgcn_mfma_f32_16x16x32_bf16(a2[kc], b, acc[n], 0, 0, 0);
    }
  }

  // ---- bias + ReLU + LN2 ----
  {
    float fb[8], lw[8], lb[8];
#pragma unroll
    for (int n = 0; n < 8; n++) {
      fb[n] = fc1b[n * 16 + c];
      lw[n] = ln2w[n * 16 + c]; lb[n] = ln2b[n * 16 + c];
    }
#pragma unroll
    for (int r = 0; r < 4; r++) {
#pragma unroll
      for (int n = 0; n < 8; n++) acc[n][r] = fmaxf(acc[n][r] + fb[n], 0.f);
      float s1 = 0.f, s2 = 0.f;
#pragma unroll
      for (int n = 0; n < 8; n++) { float v = acc[n][r]; s1 += v; s2 += v * v; }
#pragma unroll
      for (int off = 1; off < 16; off <<= 1) {
        s1 += __shfl_xor(s1, off); s2 += __shfl_xor(s2, off);
      }
      float mu = s1 * (1.f / 128.f);
      float var = fmaxf(s2 * (1.f / 128.f) - mu * mu, 0.f);
      float rs = rsqrtf(var + GEPS);
#pragma unroll
      for (int n = 0; n < 8; n++)
        acc[n][r] = (acc[n][r] - mu) * rs * lw[n] + lb[n];
    }
  }
  __syncthreads();   // all GEMM2 frag reads done before overwrite

  // ---- H2 -> lsA (A-layout) ----
#pragma unroll
  for (int r = 0; r < 4; r++)
#pragma unroll
    for (int n = 0; n < 8; n++)
      lsA[(wv * 16 + q * 4 + r) * 168 + n * 16 + c] = f2bf(acc[n][r]);
  __syncthreads();

  // ---- fc2 (16-col padded tile) + mean-atomic ----
  short8 a3[4];
#pragma unroll
  for (int kc = 0; kc < 4; kc++) a3[kc] = *(const short8*)(pa + kc * 32);
  floatx4 o4 = (floatx4){0.f, 0.f, 0.f, 0.f};
#pragma unroll
  for (int kc = 0; kc < 4; kc++) {
    short8 b = *(const short8*)(W2f + kc * 512 + lane * 8);
    o4 = __builtin_amdgcn_mfma_f32_16x16x32_bf16(a3[kc], b, o4, 0, 0, 0);
  }
  if (c < NCLS) {
    float bias = fc2b[c];
#pragma unroll
    for (int r = 0; r < 4; r++)
      atomicAdd(out + (size_t)(b0 + wv * 16 + q * 4 + r) * NCLS + c,
                (o4[r] + bias) * 0.01f);
  }
}

// ---------------------------------------------------------------------------
extern "C" void kernel_launch(void* const* d_in, const int* in_sizes, int n_in,
                              void* d_out, int out_size, void* d_ws, size_t ws_size,
                              hipStream_t stream)
{
  (void)in_sizes; (void)n_in; (void)ws_size;
  const float* x    = (const float*)d_in[0];
  const float* w1   = (const float*)d_in[1];
  const float* b1   = (const float*)d_in[2];
  const int*   perm = (const int*)d_in[3];
  const float* gn1w = (const float*)d_in[4];
  const float* gn1b = (const float*)d_in[5];
  const float* c2w  = (const float*)d_in[6];
  const float* c2b  = (const float*)d_in[7];
  const float* gn2w = (const float*)d_in[8];
  const float* gn2b = (const float*)d_in[9];
  const float* c3w  = (const float*)d_in[10];
  const float* c3b  = (const float*)d_in[11];
  const int*   swr  = (const int*)d_in[12];
  const float* E    = (const float*)d_in[13];
  const float* ln1w = (const float*)d_in[14];
  const float* ln1b = (const float*)d_in[15];
  const float* fc1w = (const float*)d_in[16];
  const float* fc1b = (const float*)d_in[17];
  const float* ln2w = (const float*)d_in[18];
  const float* ln2b = (const float*)d_in[19];
  const float* fc2w = (const float*)d_in[20];
  const float* fc2b = (const float*)d_in[21];
  float* out = (float*)d_out;

  // workspace layout:
  //   [0, 26.2MB)       : wT logits f32 [1600][B]   (persists through k3)
  //   [26.2MB, +4.10MB) : Bf (100*20480 shorts)
  //   then W1f 32,768 B, W2f 4,096 B
  const size_t W_BYTES = (size_t)NB * NRODT * 4;     // 26,214,400
  float* wTbuf = (float*)d_ws;
  unsigned short* Bfb   = (unsigned short*)((char*)d_ws + W_BYTES);
  unsigned short* W1fb  = (unsigned short*)((char*)d_ws + W_BYTES + 4096000);
  unsigned short* W2fb  = (unsigned short*)((char*)d_ws + W_BYTES + 4096000 + 32768);

  hipMemsetAsync(d_out, 0, (size_t)out_size * sizeof(float), stream);
  dim3 g1(NB / 8, 4);
  k1_w<<<g1, 256, 0, stream>>>(x, w1, b1, perm, gn1w, gn1b, c2w, c2b,
                               gn2w, gn2b, c3w, c3b, wTbuf);
  k0_prep<<<NFOR + 2, 256, 0, stream>>>(E, swr, fc1w, fc2w, Bfb, W1fb, W2fb);
  dim3 g3(NB / 64, NFOR);
  k3_mfma<<<g3, 256, 0, stream>>>(wTbuf, swr, Bfb, W1fb, W2fb,
                                  ln1w, ln1b, fc1b, ln2w, ln2b, fc2b, out);
}

// Round 7
// 255.777 us; speedup vs baseline: 1.5797x; 1.0737x over previous
//
#include <hip/hip_runtime.h>
#include <hip/hip_bf16.h>
#include <stdint.h>

#define NB 4096
#define NCOL 100
#define NCOND 64
#define NTOTAL 6400
#define NRODT 1600
#define NEST 160
#define NFOR 100
#define NHID 128
#define NCLS 10
#define GEPS 1e-5f

typedef __attribute__((ext_vector_type(8))) short short8;
typedef __attribute__((ext_vector_type(4))) float floatx4;

// round-half-up f32->bf16: 2 VALU ops (vs ~4 for RNE); tie-only difference
__device__ __forceinline__ unsigned f2bfu(float x) {
  union { float f; unsigned u; } v; v.f = x;
  return (v.u + 0x8000u) >> 16;
}

// ---------------------------------------------------------------------------
// K1: fused ConditionGeneration + perm + phi_2 -> TRANSPOSED logits wT[g][b].
// grid (NB/64, NRODT/64), block 256 = 64 g x 4 quarters.  Thread (g, i4)
// computes b = k*16 + i4*4 + j; store k is a float4 with lanes i4=0..3
// contiguous => 64 B full-line runs, 16 g-rows per store instruction.
// ---------------------------------------------------------------------------
__global__ __launch_bounds__(256) void k1_w(
    const float* __restrict__ x, const float* __restrict__ w1,
    const float* __restrict__ b1, const int* __restrict__ perm,
    const float* __restrict__ gn1w, const float* __restrict__ gn1b,
    const float* __restrict__ c2w, const float* __restrict__ c2b,
    const float* __restrict__ gn2w, const float* __restrict__ gn2b,
    const float* __restrict__ c3w, const float* __restrict__ c3b,
    float* __restrict__ wT)
{
  __shared__ float xl[64 * NCOL];          // 25.6 KB
  const int b0 = blockIdx.x * 64;
  const int g  = blockIdx.y * 64 + (threadIdx.x >> 2);
  const int i4 = threadIdx.x & 3;
  for (int i = threadIdx.x; i < 64 * NCOL; i += 256)
    xl[i] = x[(size_t)b0 * NCOL + i];
  __syncthreads();

  const int4 p4 = *(const int4*)(perm + 4 * g);
  const int pv[4] = {p4.x, p4.y, p4.z, p4.w};
  float w1v[4], b1v[4];
  int pc[4];
#pragma unroll
  for (int i = 0; i < 4; i++) {
    unsigned p = (unsigned)pv[i];
    unsigned j = p / 100u;
    unsigned cc = p - j * 100u;
    pc[i] = (int)cc;
    w1v[i] = w1[cc * NCOND + j];
    b1v[i] = b1[cc * NCOND + j];
  }
  const float4 g1w = *(const float4*)(gn1w + 4 * g);
  const float4 g1b = *(const float4*)(gn1b + 4 * g);
  const float4 cw0 = *(const float4*)(c2w + 16 * g);
  const float4 cw1 = *(const float4*)(c2w + 16 * g + 4);
  const float4 cw2 = *(const float4*)(c2w + 16 * g + 8);
  const float4 cw3 = *(const float4*)(c2w + 16 * g + 12);
  const float4 cbv = *(const float4*)(c2b + 4 * g);
  const float4 g2w = *(const float4*)(gn2w + 4 * g);
  const float4 g2b = *(const float4*)(gn2b + 4 * g);
  const float4 c3v = *(const float4*)(c3w + 4 * g);
  const float c3bv = c3b[g];

  for (int k = 0; k < 4; k++) {
    float v4[4];
#pragma unroll
    for (int j = 0; j < 4; j++) {
      const int bb = k * 16 + i4 * 4 + j;
      float O[4];
#pragma unroll
      for (int i = 0; i < 4; i++) {
        float a = xl[bb * NCOL + pc[i]] * w1v[i] + b1v[i];
        O[i] = 1.0f / (1.0f + __expf(-a));
      }
      float mu = 0.25f * (O[0] + O[1] + O[2] + O[3]);
      float d[4], var = 0.f;
#pragma unroll
      for (int i = 0; i < 4; i++) { d[i] = O[i] - mu; var += d[i] * d[i]; }
      float rs = rsqrtf(0.25f * var + GEPS);
      float xn0 = d[0] * rs * g1w.x + g1b.x;
      float xn1 = d[1] * rs * g1w.y + g1b.y;
      float xn2 = d[2] * rs * g1w.z + g1b.z;
      float xn3 = d[3] * rs * g1w.w + g1b.w;
      float h[4];
      h[0] = xn0*cw0.x + xn1*cw1.x + xn2*cw2.x + xn3*cw3.x + cbv.x;
      h[1] = xn0*cw0.y + xn1*cw1.y + xn2*cw2.y + xn3*cw3.y + cbv.y;
      h[2] = xn0*cw0.z + xn1*cw1.z + xn2*cw2.z + xn3*cw3.z + cbv.z;
      h[3] = xn0*cw0.w + xn1*cw1.w + xn2*cw2.w + xn3*cw3.w + cbv.w;
#pragma unroll
      for (int i = 0; i < 4; i++) h[i] = fmaxf(h[i], 0.f);
      float mu2 = 0.25f * (h[0] + h[1] + h[2] + h[3]);
      float e[4], var2 = 0.f;
#pragma unroll
      for (int i = 0; i < 4; i++) { e[i] = h[i] - mu2; var2 += e[i] * e[i]; }
      float rs2 = rsqrtf(0.25f * var2 + GEPS);
      float hn0 = e[0] * rs2 * g2w.x + g2b.x;
      float hn1 = e[1] * rs2 * g2w.y + g2b.y;
      float hn2 = e[2] * rs2 * g2w.z + g2b.z;
      float hn3 = e[3] * rs2 * g2w.w + g2b.w;
      v4[j] = hn0*c3v.x + hn1*c3v.y + hn2*c3v.z + hn3*c3v.w + c3bv;
    }
    *(float4*)(wT + (size_t)g * NB + b0 + k * 16 + i4 * 4) =
        make_float4(v4[0], v4[1], v4[2], v4[3]);
  }
}

// ---------------------------------------------------------------------------
// K0: fragment-pack B operands.
//  blocks 0..99 : Bf[f][n=8][kc=5][lane=64][8]  = E[swr[f][kc*32+q*8+j]][n*16+c]
//  block  100   : W1f[n=8][kc=4][lane][8]       = fc1w[kc*32+q*8+j][n*16+c]
//  block  101   : W2f[kc=4][lane][8]            = c<10 ? fc2w[k][c] : 0
// ---------------------------------------------------------------------------
__global__ __launch_bounds__(256) void k0_prep(
    const float* __restrict__ E, const int* __restrict__ swr,
    const float* __restrict__ fc1w, const float* __restrict__ fc2w,
    unsigned short* __restrict__ Bf, unsigned short* __restrict__ W1f,
    unsigned short* __restrict__ W2f)
{
  __shared__ int ridx[NEST];
  const int tid = threadIdx.x;
  const int blk = blockIdx.x;

  if (blk < NFOR) {
    if (tid < NEST) ridx[tid] = swr[blk * NEST + tid];
    __syncthreads();
    for (int m = tid; m < 2560; m += 256) {        // m = (n*5+kc)*64 + lane
      int lane = m & 63, rest = m >> 6;
      int kc = rest % 5, n = rest / 5;
      int q = lane >> 4, c = lane & 15;
      int e0 = kc * 32 + q * 8;
      int h = n * 16 + c;
      union { unsigned short v[8]; uint4 u; } t;
#pragma unroll
      for (int j = 0; j < 8; j++)
        t.v[j] = (unsigned short)f2bfu(E[(size_t)ridx[e0 + j] * NHID + h]);
      *(uint4*)(Bf + (size_t)blk * 20480 + (size_t)m * 8) = t.u;
    }
  } else if (blk == NFOR) {
    for (int m = tid; m < 2048; m += 256) {        // m = (n*4+kc)*64 + lane
      int lane = m & 63, rest = m >> 6;
      int kc = rest & 3, n = rest >> 2;
      int q = lane >> 4, c = lane & 15;
      int k0 = kc * 32 + q * 8;
      int o = n * 16 + c;
      union { unsigned short v[8]; uint4 u; } t;
#pragma unroll
      for (int j = 0; j < 8; j++)
        t.v[j] = (unsigned short)f2bfu(fc1w[(size_t)(k0 + j) * NHID + o]);
      *(uint4*)(W1f + (size_t)m * 8) = t.u;
    }
  } else {
    for (int m = tid; m < 256; m += 256) {         // m = kc*64 + lane
      int lane = m & 63, kc = m >> 6;
      int q = lane >> 4, c = lane & 15;
      int k0 = kc * 32 + q * 8;
      union { unsigned short v[8]; uint4 u; } t;
#pragma unroll
      for (int j = 0; j < 8; j++)
        t.v[j] = (unsigned short)f2bfu(c < NCLS ? fc2w[(size_t)(k0 + j) * NCLS + c] : 0.f);
      *(uint4*)(W2f + (size_t)m * 8) = t.u;
    }
  }
}

// ---------------------------------------------------------------------------
// K3: register-gather softmax + MFMA pipeline, ONE barrier total.
// Thread t owns (row r=t>>2, e-chunk ch=t&3): 40 coalesced global loads
// straight to registers, softmax reduce over 4 ADJACENT lanes (shfl_xor 1,2),
// packed bf16 written directly into lsA's A-layout row.  All lsA traffic is
// wave-private (rows 16wv..16wv+15 <-> lanes of wave wv); DS ops are in-order
// per wave -> no __syncthreads needed after the ridx stage.
// ---------------------------------------------------------------------------
__global__ __launch_bounds__(256, 4) void k3_mfma(
    const float* __restrict__ wT,             // [1600][B] f32 logits^T
    const int* __restrict__ swr,
    const unsigned short* __restrict__ Bf,    // [f][8][5][64][8]
    const unsigned short* __restrict__ W1f,   // [8][4][64][8]
    const unsigned short* __restrict__ W2f,   // [4][64][8]
    const float* __restrict__ ln1w, const float* __restrict__ ln1b,
    const float* __restrict__ fc1b,
    const float* __restrict__ ln2w, const float* __restrict__ ln2b,
    const float* __restrict__ fc2b,
    float* __restrict__ out)
{
  __shared__ unsigned short lsA[64 * 168];    // 21504 B
  __shared__ int ridx[NEST];

  const int tid = threadIdx.x;
  const int b0 = blockIdx.x * 64;
  const int f  = blockIdx.y;
  const int lane = tid & 63, wv = tid >> 6;
  const int c = lane & 15, q = lane >> 4;

  if (tid < NEST) ridx[tid] = swr[f * NEST + tid];
  __syncthreads();                     // the ONLY block-wide barrier

  // ---- gather 40 logits to registers (coalesced: 4 rows x 64 B / instr) ----
  const int r = tid >> 2, ch = tid & 3;
  const float* wcol = wT + b0 + r;
  const int* rp = ridx + ch * 40;
  float g[40];
#pragma unroll
  for (int j = 0; j < 40; j++)
    g[j] = wcol[(size_t)rp[j] * NB];

  // ---- softmax over row r (4 adjacent lanes x 40 values) ----
  float mx = -1e30f;
#pragma unroll
  for (int j = 0; j < 40; j++) mx = fmaxf(mx, g[j]);
  mx = fmaxf(mx, __shfl_xor(mx, 1));
  mx = fmaxf(mx, __shfl_xor(mx, 2));
  float s = 0.f;
#pragma unroll
  for (int j = 0; j < 40; j++) { g[j] = __expf(g[j] - mx); s += g[j]; }
  s += __shfl_xor(s, 1);
  s += __shfl_xor(s, 2);
  const float inv = 1.0f / s;

  // ---- pack ws row straight into A-layout lsA (wave-private strip) ----
  unsigned* dst = (unsigned*)(lsA + r * 168) + ch * 20;
#pragma unroll
  for (int k = 0; k < 20; k++) {
    unsigned u0 = f2bfu(g[2 * k] * inv);
    unsigned u1 = f2bfu(g[2 * k + 1] * inv);
    dst[k] = u0 | (u1 << 16);
  }

  // ---- GEMM1: F = ws[64x160] @ Ep[160x128] ----
  const unsigned short* pa = lsA + (wv * 16 + c) * 168 + q * 8;
  short8 a1[5];
#pragma unroll
  for (int kc = 0; kc < 5; kc++) a1[kc] = *(const short8*)(pa + kc * 32);

  floatx4 acc[8];
#pragma unroll
  for (int n = 0; n < 8; n++) acc[n] = (floatx4){0.f, 0.f, 0.f, 0.f};

  const unsigned short* bbase = Bf + (size_t)f * 20480 + lane * 8;
#pragma unroll
  for (int n = 0; n < 8; n++) {
    const unsigned short* bp = bbase + n * 2560;
#pragma unroll
    for (int kc = 0; kc < 5; kc++) {
      short8 b = *(const short8*)(bp + kc * 512);
      acc[n] = __builtin_amdgcn_mfma_f32_16x16x32_bf16(a1[kc], b, acc[n], 0, 0, 0);
    }
  }

  // ---- LN1 (C-layout: row=q*4+rr, col=16n+c; reduce over 16 lanes) ----
  {
    float lw[8], lb[8];
#pragma unroll
    for (int n = 0; n < 8; n++) { lw[n] = ln1w[n * 16 + c]; lb[n] = ln1b[n * 16 + c]; }
#pragma unroll
    for (int rr = 0; rr < 4; rr++) {
      float s1 = 0.f, s2 = 0.f;
#pragma unroll
      for (int n = 0; n < 8; n++) { float v = acc[n][rr]; s1 += v; s2 += v * v; }
#pragma unroll
      for (int off = 1; off < 16; off <<= 1) {
        s1 += __shfl_xor(s1, off); s2 += __shfl_xor(s2, off);
      }
      float mu = s1 * (1.f / 128.f);
      float var = fmaxf(s2 * (1.f / 128.f) - mu * mu, 0.f);
      float rs = rsqrtf(var + GEPS);
#pragma unroll
      for (int n = 0; n < 8; n++)
        acc[n][rr] = (acc[n][rr] - mu) * rs * lw[n] + lb[n];
    }
  }

  // ---- Fn -> lsA (A-layout bf16, wave-private; no barrier needed) ----
#pragma unroll
  for (int rr = 0; rr < 4; rr++)
#pragma unroll
    for (int n = 0; n < 8; n++)
      lsA[(wv * 16 + q * 4 + rr) * 168 + n * 16 + c] =
          (unsigned short)f2bfu(acc[n][rr]);

  // ---- GEMM2: H = Fn[64x128] @ fc1w[128x128] ----
  short8 a2[4];
#pragma unroll
  for (int kc = 0; kc < 4; kc++) a2[kc] = *(const short8*)(pa + kc * 32);
#pragma unroll
  for (int n = 0; n < 8; n++) acc[n] = (floatx4){0.f, 0.f, 0.f, 0.f};
  const unsigned short* w1p = W1f + lane * 8;
#pragma unroll
  for (int n = 0; n < 8; n++) {
#pragma unroll
    for (int kc = 0; kc < 4; kc++) {
      short8 b = *(const short8*)(w1p + (n * 4 + kc) * 512);
      acc[n] = __builtin_amdgcn_mfma_f32_16x16x32_bf16(a2[kc], b, acc[n], 0, 0, 0);
    }
  }

  // ---- bias + ReLU + LN2 ----
  {
    float fb[8], lw[8], lb[8];
#pragma unroll
    for (int n = 0; n < 8; n++) {
      fb[n] = fc1b[n * 16 + c];
      lw[n] = ln2w[n * 16 + c]; lb[n] = ln2b[n * 16 + c];
    }
#pragma unroll
    for (int rr = 0; rr < 4; rr++) {
#pragma unroll
      for (int n = 0; n < 8; n++) acc[n][rr] = fmaxf(acc[n][rr] + fb[n], 0.f);
      float s1 = 0.f, s2 = 0.f;
#pragma unroll
      for (int n = 0; n < 8; n++) { float v = acc[n][rr]; s1 += v; s2 += v * v; }
#pragma unroll
      for (int off = 1; off < 16; off <<= 1) {
        s1 += __shfl_xor(s1, off); s2 += __shfl_xor(s2, off);
      }
      float mu = s1 * (1.f / 128.f);
      float var = fmaxf(s2 * (1.f / 128.f) - mu * mu, 0.f);
      float rs = rsqrtf(var + GEPS);
#pragma unroll
      for (int n = 0; n < 8; n++)
        acc[n][rr] = (acc[n][rr] - mu) * rs * lw[n] + lb[n];
    }
  }

  // ---- H2 -> lsA (A-layout, wave-private; no barrier) ----
#pragma unroll
  for (int rr = 0; rr < 4; rr++)
#pragma unroll
    for (int n = 0; n < 8; n++)
      lsA[(wv * 16 + q * 4 + rr) * 168 + n * 16 + c] =
          (unsigned short)f2bfu(acc[n][rr]);

  // ---- fc2 (16-col padded tile) + mean-atomic ----
  short8 a3[4];
#pragma unroll
  for (int kc = 0; kc < 4; kc++) a3[kc] = *(const short8*)(pa + kc * 32);
  floatx4 o4 = (floatx4){0.f, 0.f, 0.f, 0.f};
#pragma unroll
  for (int kc = 0; kc < 4; kc++) {
    short8 b = *(const short8*)(W2f + kc * 512 + lane * 8);
    o4 = __builtin_amdgcn_mfma_f32_16x16x32_bf16(a3[kc], b, o4, 0, 0, 0);
  }
  if (c < NCLS) {
    float bias = fc2b[c];
#pragma unroll
    for (int rr = 0; rr < 4; rr++)
      atomicAdd(out + (size_t)(b0 + wv * 16 + q * 4 + rr) * NCLS + c,
                (o4[rr] + bias) * 0.01f);
  }
}

// ---------------------------------------------------------------------------
extern "C" void kernel_launch(void* const* d_in, const int* in_sizes, int n_in,
                              void* d_out, int out_size, void* d_ws, size_t ws_size,
                              hipStream_t stream)
{
  (void)in_sizes; (void)n_in; (void)ws_size;
  const float* x    = (const float*)d_in[0];
  const float* w1   = (const float*)d_in[1];
  const float* b1   = (const float*)d_in[2];
  const int*   perm = (const int*)d_in[3];
  const float* gn1w = (const float*)d_in[4];
  const float* gn1b = (const float*)d_in[5];
  const float* c2w  = (const float*)d_in[6];
  const float* c2b  = (const float*)d_in[7];
  const float* gn2w = (const float*)d_in[8];
  const float* gn2b = (const float*)d_in[9];
  const float* c3w  = (const float*)d_in[10];
  const float* c3b  = (const float*)d_in[11];
  const int*   swr  = (const int*)d_in[12];
  const float* E    = (const float*)d_in[13];
  const float* ln1w = (const float*)d_in[14];
  const float* ln1b = (const float*)d_in[15];
  const float* fc1w = (const float*)d_in[16];
  const float* fc1b = (const float*)d_in[17];
  const float* ln2w = (const float*)d_in[18];
  const float* ln2b = (const float*)d_in[19];
  const float* fc2w = (const float*)d_in[20];
  const float* fc2b = (const float*)d_in[21];
  float* out = (float*)d_out;

  // workspace layout:
  //   [0, 26.2MB)       : wT logits f32 [1600][B]   (persists through k3)
  //   [26.2MB, +4.10MB) : Bf (100*20480 shorts)
  //   then W1f 32,768 B, W2f 4,096 B
  const size_t W_BYTES = (size_t)NB * NRODT * 4;     // 26,214,400
  float* wTbuf = (float*)d_ws;
  unsigned short* Bfb   = (unsigned short*)((char*)d_ws + W_BYTES);
  unsigned short* W1fb  = (unsigned short*)((char*)d_ws + W_BYTES + 4096000);
  unsigned short* W2fb  = (unsigned short*)((char*)d_ws + W_BYTES + 4096000 + 32768);

  hipMemsetAsync(d_out, 0, (size_t)out_size * sizeof(float), stream);
  dim3 g1(NB / 64, NRODT / 64);
  k1_w<<<g1, 256, 0, stream>>>(x, w1, b1, perm, gn1w, gn1b, c2w, c2b,
                               gn2w, gn2b, c3w, c3b, wTbuf);
  k0_prep<<<NFOR + 2, 256, 0, stream>>>(E, swr, fc1w, fc2w, Bfb, W1fb, W2fb);
  dim3 g3(NB / 64, NFOR);
  k3_mfma<<<g3, 256, 0, stream>>>(wTbuf, swr, Bfb, W1fb, W2fb,
                                  ln1w, ln1b, fc1b, ln2w, ln2b, fc2b, out);
}

// Round 8
// 248.117 us; speedup vs baseline: 1.6285x; 1.0309x over previous
//
#include <hip/hip_runtime.h>
#include <hip/hip_bf16.h>
#include <stdint.h>

#define NB 4096
#define NCOL 100
#define NCOND 64
#define NTOTAL 6400
#define NRODT 1600
#define NEST 160
#define NFOR 100
#define NHID 128
#define NCLS 10
#define GEPS 1e-5f

typedef __attribute__((ext_vector_type(8))) short short8;
typedef __attribute__((ext_vector_type(4))) float floatx4;

// round-half-up f32->bf16: 2 VALU ops; tie-only difference vs RNE
__device__ __forceinline__ unsigned f2bfu(float x) {
  union { float f; unsigned u; } v; v.f = x;
  return (v.u + 0x8000u) >> 16;
}

// ---------------------------------------------------------------------------
// K01: merged prep kernel (single launch).
//  blocks [0,1600)    : k1 -- ConditionGeneration+perm+phi_2 -> wT[g][b]
//  blocks [1600,1702) : k0 -- fragment-pack Bf / W1f / W2f
//  blocks [1702,1705) : zero d_out (re-poisoned to 0xAA by harness)
// ---------------------------------------------------------------------------
__global__ __launch_bounds__(256) void k01_prep(
    const float* __restrict__ x, const float* __restrict__ w1,
    const float* __restrict__ b1, const int* __restrict__ perm,
    const float* __restrict__ gn1w, const float* __restrict__ gn1b,
    const float* __restrict__ c2w, const float* __restrict__ c2b,
    const float* __restrict__ gn2w, const float* __restrict__ gn2b,
    const float* __restrict__ c3w, const float* __restrict__ c3b,
    const float* __restrict__ E, const int* __restrict__ swr,
    const float* __restrict__ fc1w, const float* __restrict__ fc2w,
    float* __restrict__ wT,
    unsigned short* __restrict__ Bf, unsigned short* __restrict__ W1f,
    unsigned short* __restrict__ W2f, float* __restrict__ out)
{
  __shared__ float xl[64 * NCOL];          // k1 path only (25.6 KB)
  __shared__ int ridx[NEST];               // k0 path only
  const int tid = threadIdx.x;
  const int blk = blockIdx.x;

  if (blk < 1600) {
    // ---------------- k1: phi_2 logits, transposed output ----------------
    const int b0 = (blk & 63) * 64;
    const int g  = (blk >> 6) * 64 + (tid >> 2);
    const int i4 = tid & 3;
    for (int i = tid; i < 64 * NCOL; i += 256)
      xl[i] = x[(size_t)b0 * NCOL + i];
    __syncthreads();

    const int4 p4 = *(const int4*)(perm + 4 * g);
    const int pv[4] = {p4.x, p4.y, p4.z, p4.w};
    float w1v[4], b1v[4];
    int pc[4];
#pragma unroll
    for (int i = 0; i < 4; i++) {
      unsigned p = (unsigned)pv[i];
      unsigned j = p / 100u;
      unsigned cc = p - j * 100u;
      pc[i] = (int)cc;
      w1v[i] = w1[cc * NCOND + j];
      b1v[i] = b1[cc * NCOND + j];
    }
    const float4 g1w = *(const float4*)(gn1w + 4 * g);
    const float4 g1b = *(const float4*)(gn1b + 4 * g);
    const float4 cw0 = *(const float4*)(c2w + 16 * g);
    const float4 cw1 = *(const float4*)(c2w + 16 * g + 4);
    const float4 cw2 = *(const float4*)(c2w + 16 * g + 8);
    const float4 cw3 = *(const float4*)(c2w + 16 * g + 12);
    const float4 cbv = *(const float4*)(c2b + 4 * g);
    const float4 g2w = *(const float4*)(gn2w + 4 * g);
    const float4 g2b = *(const float4*)(gn2b + 4 * g);
    const float4 c3v = *(const float4*)(c3w + 4 * g);
    const float c3bv = c3b[g];

    for (int k = 0; k < 4; k++) {
      float v4[4];
#pragma unroll
      for (int j = 0; j < 4; j++) {
        const int bb = k * 16 + i4 * 4 + j;
        float O[4];
#pragma unroll
        for (int i = 0; i < 4; i++) {
          float a = xl[bb * NCOL + pc[i]] * w1v[i] + b1v[i];
          O[i] = 1.0f / (1.0f + __expf(-a));
        }
        float mu = 0.25f * (O[0] + O[1] + O[2] + O[3]);
        float d[4], var = 0.f;
#pragma unroll
        for (int i = 0; i < 4; i++) { d[i] = O[i] - mu; var += d[i] * d[i]; }
        float rs = rsqrtf(0.25f * var + GEPS);
        float xn0 = d[0] * rs * g1w.x + g1b.x;
        float xn1 = d[1] * rs * g1w.y + g1b.y;
        float xn2 = d[2] * rs * g1w.z + g1b.z;
        float xn3 = d[3] * rs * g1w.w + g1b.w;
        float h[4];
        h[0] = xn0*cw0.x + xn1*cw1.x + xn2*cw2.x + xn3*cw3.x + cbv.x;
        h[1] = xn0*cw0.y + xn1*cw1.y + xn2*cw2.y + xn3*cw3.y + cbv.y;
        h[2] = xn0*cw0.z + xn1*cw1.z + xn2*cw2.z + xn3*cw3.z + cbv.z;
        h[3] = xn0*cw0.w + xn1*cw1.w + xn2*cw2.w + xn3*cw3.w + cbv.w;
#pragma unroll
        for (int i = 0; i < 4; i++) h[i] = fmaxf(h[i], 0.f);
        float mu2 = 0.25f * (h[0] + h[1] + h[2] + h[3]);
        float e[4], var2 = 0.f;
#pragma unroll
        for (int i = 0; i < 4; i++) { e[i] = h[i] - mu2; var2 += e[i] * e[i]; }
        float rs2 = rsqrtf(0.25f * var2 + GEPS);
        float hn0 = e[0] * rs2 * g2w.x + g2b.x;
        float hn1 = e[1] * rs2 * g2w.y + g2b.y;
        float hn2 = e[2] * rs2 * g2w.z + g2b.z;
        float hn3 = e[3] * rs2 * g2w.w + g2b.w;
        v4[j] = hn0*c3v.x + hn1*c3v.y + hn2*c3v.z + hn3*c3v.w + c3bv;
      }
      *(float4*)(wT + (size_t)g * NB + b0 + k * 16 + i4 * 4) =
          make_float4(v4[0], v4[1], v4[2], v4[3]);
    }
  } else if (blk < 1600 + NFOR) {
    // ---------------- k0: Bf fragment pack ----------------
    const int fblk = blk - 1600;
    if (tid < NEST) ridx[tid] = swr[fblk * NEST + tid];
    __syncthreads();
    for (int m = tid; m < 2560; m += 256) {        // m = (n*5+kc)*64 + lane
      int lane = m & 63, rest = m >> 6;
      int kc = rest % 5, n = rest / 5;
      int q = lane >> 4, c = lane & 15;
      int e0 = kc * 32 + q * 8;
      int h = n * 16 + c;
      union { unsigned short v[8]; uint4 u; } t;
#pragma unroll
      for (int j = 0; j < 8; j++)
        t.v[j] = (unsigned short)f2bfu(E[(size_t)ridx[e0 + j] * NHID + h]);
      *(uint4*)(Bf + (size_t)fblk * 20480 + (size_t)m * 8) = t.u;
    }
  } else if (blk == 1600 + NFOR) {
    // ---------------- k0: W1f ----------------
    for (int m = tid; m < 2048; m += 256) {        // m = (n*4+kc)*64 + lane
      int lane = m & 63, rest = m >> 6;
      int kc = rest & 3, n = rest >> 2;
      int q = lane >> 4, c = lane & 15;
      int k0 = kc * 32 + q * 8;
      int o = n * 16 + c;
      union { unsigned short v[8]; uint4 u; } t;
#pragma unroll
      for (int j = 0; j < 8; j++)
        t.v[j] = (unsigned short)f2bfu(fc1w[(size_t)(k0 + j) * NHID + o]);
      *(uint4*)(W1f + (size_t)m * 8) = t.u;
    }
  } else if (blk == 1601 + NFOR) {
    // ---------------- k0: W2f ----------------
    for (int m = tid; m < 256; m += 256) {         // m = kc*64 + lane
      int lane = m & 63, kc = m >> 6;
      int q = lane >> 4, c = lane & 15;
      int k0 = kc * 32 + q * 8;
      union { unsigned short v[8]; uint4 u; } t;
#pragma unroll
      for (int j = 0; j < 8; j++)
        t.v[j] = (unsigned short)f2bfu(c < NCLS ? fc2w[(size_t)(k0 + j) * NCLS + c] : 0.f);
      *(uint4*)(W2f + (size_t)m * 8) = t.u;
    }
  } else {
    // ---------------- zero d_out (3 blocks) ----------------
    const int z = blk - (1602 + NFOR);
    float4 zz = make_float4(0.f, 0.f, 0.f, 0.f);
    for (int i = z * 256 + tid; i < NB * NCLS / 4; i += 3 * 256)
      ((float4*)out)[i] = zz;
  }
}

// ---------------------------------------------------------------------------
// K3: register-gather softmax + MFMA pipeline, one barrier.
// launch_bounds(256,6): LDS 22.5KB allows 7 blocks/CU; 6 waves/EU needs
// <=85 total regs (44 arch + 32 acc observed at (256,4)).
// GEMM loops kc-outer so only one A-frag is live at a time.
// ---------------------------------------------------------------------------
__global__ __launch_bounds__(256, 6) void k3_mfma(
    const float* __restrict__ wT,             // [1600][B] f32 logits^T
    const int* __restrict__ swr,
    const unsigned short* __restrict__ Bf,    // [f][8][5][64][8]
    const unsigned short* __restrict__ W1f,   // [8][4][64][8]
    const unsigned short* __restrict__ W2f,   // [4][64][8]
    const float* __restrict__ ln1w, const float* __restrict__ ln1b,
    const float* __restrict__ fc1b,
    const float* __restrict__ ln2w, const float* __restrict__ ln2b,
    const float* __restrict__ fc2b,
    float* __restrict__ out)
{
  __shared__ unsigned short lsA[64 * 168];    // 21504 B
  __shared__ int ridx[NEST];

  const int tid = threadIdx.x;
  const int b0 = blockIdx.x * 64;
  const int f  = blockIdx.y;
  const int lane = tid & 63, wv = tid >> 6;
  const int c = lane & 15, q = lane >> 4;

  if (tid < NEST) ridx[tid] = swr[f * NEST + tid];
  __syncthreads();                     // the ONLY block-wide barrier

  // ---- gather 40 logits to registers (4 lines per wave-instr) ----
  const int r = tid >> 2, ch = tid & 3;
  const float* wcol = wT + b0 + r;
  const int* rp = ridx + ch * 40;
  float g[40];
#pragma unroll
  for (int j = 0; j < 40; j++)
    g[j] = wcol[(size_t)rp[j] * NB];

  // ---- softmax over row r (4 adjacent lanes x 40 values) ----
  float mx = -1e30f;
#pragma unroll
  for (int j = 0; j < 40; j++) mx = fmaxf(mx, g[j]);
  mx = fmaxf(mx, __shfl_xor(mx, 1));
  mx = fmaxf(mx, __shfl_xor(mx, 2));
  float s = 0.f;
#pragma unroll
  for (int j = 0; j < 40; j++) { g[j] = __expf(g[j] - mx); s += g[j]; }
  s += __shfl_xor(s, 1);
  s += __shfl_xor(s, 2);
  const float inv = 1.0f / s;

  // ---- pack ws row straight into A-layout lsA (wave-private strip) ----
  unsigned* dst = (unsigned*)(lsA + r * 168) + ch * 20;
#pragma unroll
  for (int k = 0; k < 20; k++) {
    unsigned u0 = f2bfu(g[2 * k] * inv);
    unsigned u1 = f2bfu(g[2 * k + 1] * inv);
    dst[k] = u0 | (u1 << 16);
  }

  // ---- GEMM1: F = ws[64x160] @ Ep[160x128]  (kc-outer, 1 live A-frag) ----
  const unsigned short* pa = lsA + (wv * 16 + c) * 168 + q * 8;
  floatx4 acc[8];
#pragma unroll
  for (int n = 0; n < 8; n++) acc[n] = (floatx4){0.f, 0.f, 0.f, 0.f};

  const unsigned short* bbase = Bf + (size_t)f * 20480 + lane * 8;
#pragma unroll
  for (int kc = 0; kc < 5; kc++) {
    short8 a = *(const short8*)(pa + kc * 32);
#pragma unroll
    for (int n = 0; n < 8; n++) {
      short8 b = *(const short8*)(bbase + n * 2560 + kc * 512);
      acc[n] = __builtin_amdgcn_mfma_f32_16x16x32_bf16(a, b, acc[n], 0, 0, 0);
    }
  }

  // ---- LN1 (C-layout: row=q*4+rr, col=16n+c; reduce over 16 lanes) ----
  {
    float lw[8], lb[8];
#pragma unroll
    for (int n = 0; n < 8; n++) { lw[n] = ln1w[n * 16 + c]; lb[n] = ln1b[n * 16 + c]; }
#pragma unroll
    for (int rr = 0; rr < 4; rr++) {
      float s1 = 0.f, s2 = 0.f;
#pragma unroll
      for (int n = 0; n < 8; n++) { float v = acc[n][rr]; s1 += v; s2 += v * v; }
#pragma unroll
      for (int off = 1; off < 16; off <<= 1) {
        s1 += __shfl_xor(s1, off); s2 += __shfl_xor(s2, off);
      }
      float mu = s1 * (1.f / 128.f);
      float var = fmaxf(s2 * (1.f / 128.f) - mu * mu, 0.f);
      float rs = rsqrtf(var + GEPS);
#pragma unroll
      for (int n = 0; n < 8; n++)
        acc[n][rr] = (acc[n][rr] - mu) * rs * lw[n] + lb[n];
    }
  }

  // ---- Fn -> lsA (A-layout bf16, wave-private; no barrier needed) ----
#pragma unroll
  for (int rr = 0; rr < 4; rr++)
#pragma unroll
    for (int n = 0; n < 8; n++)
      lsA[(wv * 16 + q * 4 + rr) * 168 + n * 16 + c] =
          (unsigned short)f2bfu(acc[n][rr]);

  // ---- GEMM2: H = Fn[64x128] @ fc1w[128x128]  (kc-outer) ----
  {
    short8 a0 = *(const short8*)(pa);
    short8 a1 = *(const short8*)(pa + 32);
    short8 a2 = *(const short8*)(pa + 64);
    short8 a3 = *(const short8*)(pa + 96);
#pragma unroll
    for (int n = 0; n < 8; n++) acc[n] = (floatx4){0.f, 0.f, 0.f, 0.f};
    const unsigned short* w1p = W1f + lane * 8;
#pragma unroll
    for (int n = 0; n < 8; n++) {
      const unsigned short* wp = w1p + n * 2048;
      acc[n] = __builtin_amdgcn_mfma_f32_16x16x32_bf16(a0, *(const short8*)(wp),        acc[n], 0, 0, 0);
      acc[n] = __builtin_amdgcn_mfma_f32_16x16x32_bf16(a1, *(const short8*)(wp + 512),  acc[n], 0, 0, 0);
      acc[n] = __builtin_amdgcn_mfma_f32_16x16x32_bf16(a2, *(const short8*)(wp + 1024), acc[n], 0, 0, 0);
      acc[n] = __builtin_amdgcn_mfma_f32_16x16x32_bf16(a3, *(const short8*)(wp + 1536), acc[n], 0, 0, 0);
    }
  }

  // ---- bias + ReLU + LN2 ----
  {
    float fb[8], lw[8], lb[8];
#pragma unroll
    for (int n = 0; n < 8; n++) {
      fb[n] = fc1b[n * 16 + c];
      lw[n] = ln2w[n * 16 + c]; lb[n] = ln2b[n * 16 + c];
    }
#pragma unroll
    for (int rr = 0; rr < 4; rr++) {
#pragma unroll
      for (int n = 0; n < 8; n++) acc[n][rr] = fmaxf(acc[n][rr] + fb[n], 0.f);
      float s1 = 0.f, s2 = 0.f;
#pragma unroll
      for (int n = 0; n < 8; n++) { float v = acc[n][rr]; s1 += v; s2 += v * v; }
#pragma unroll
      for (int off = 1; off < 16; off <<= 1) {
        s1 += __shfl_xor(s1, off); s2 += __shfl_xor(s2, off);
      }
      float mu = s1 * (1.f / 128.f);
      float var = fmaxf(s2 * (1.f / 128.f) - mu * mu, 0.f);
      float rs = rsqrtf(var + GEPS);
#pragma unroll
      for (int n = 0; n < 8; n++)
        acc[n][rr] = (acc[n][rr] - mu) * rs * lw[n] + lb[n];
    }
  }

  // ---- H2 -> lsA (A-layout, wave-private; no barrier) ----
#pragma unroll
  for (int rr = 0; rr < 4; rr++)
#pragma unroll
    for (int n = 0; n < 8; n++)
      lsA[(wv * 16 + q * 4 + rr) * 168 + n * 16 + c] =
          (unsigned short)f2bfu(acc[n][rr]);

  // ---- fc2 (16-col padded tile) + mean-atomic ----
  floatx4 o4 = (floatx4){0.f, 0.f, 0.f, 0.f};
#pragma unroll
  for (int kc = 0; kc < 4; kc++) {
    short8 a = *(const short8*)(pa + kc * 32);
    short8 b = *(const short8*)(W2f + kc * 512 + lane * 8);
    o4 = __builtin_amdgcn_mfma_f32_16x16x32_bf16(a, b, o4, 0, 0, 0);
  }
  if (c < NCLS) {
    float bias = fc2b[c];
#pragma unroll
    for (int rr = 0; rr < 4; rr++)
      atomicAdd(out + (size_t)(b0 + wv * 16 + q * 4 + rr) * NCLS + c,
                (o4[rr] + bias) * 0.01f);
  }
}

// ---------------------------------------------------------------------------
extern "C" void kernel_launch(void* const* d_in, const int* in_sizes, int n_in,
                              void* d_out, int out_size, void* d_ws, size_t ws_size,
                              hipStream_t stream)
{
  (void)in_sizes; (void)n_in; (void)ws_size; (void)out_size;
  const float* x    = (const float*)d_in[0];
  const float* w1   = (const float*)d_in[1];
  const float* b1   = (const float*)d_in[2];
  const int*   perm = (const int*)d_in[3];
  const float* gn1w = (const float*)d_in[4];
  const float* gn1b = (const float*)d_in[5];
  const float* c2w  = (const float*)d_in[6];
  const float* c2b  = (const float*)d_in[7];
  const float* gn2w = (const float*)d_in[8];
  const float* gn2b = (const float*)d_in[9];
  const float* c3w  = (const float*)d_in[10];
  const float* c3b  = (const float*)d_in[11];
  const int*   swr  = (const int*)d_in[12];
  const float* E    = (const float*)d_in[13];
  const float* ln1w = (const float*)d_in[14];
  const float* ln1b = (const float*)d_in[15];
  const float* fc1w = (const float*)d_in[16];
  const float* fc1b = (const float*)d_in[17];
  const float* ln2w = (const float*)d_in[18];
  const float* ln2b = (const float*)d_in[19];
  const float* fc2w = (const float*)d_in[20];
  const float* fc2b = (const float*)d_in[21];
  float* out = (float*)d_out;

  // workspace layout:
  //   [0, 26.2MB)       : wT logits f32 [1600][B]   (persists through k3)
  //   [26.2MB, +4.10MB) : Bf (100*20480 shorts)
  //   then W1f 32,768 B, W2f 4,096 B
  const size_t W_BYTES = (size_t)NB * NRODT * 4;     // 26,214,400
  float* wTbuf = (float*)d_ws;
  unsigned short* Bfb   = (unsigned short*)((char*)d_ws + W_BYTES);
  unsigned short* W1fb  = (unsigned short*)((char*)d_ws + W_BYTES + 4096000);
  unsigned short* W2fb  = (unsigned short*)((char*)d_ws + W_BYTES + 4096000 + 32768);

  k01_prep<<<1600 + NFOR + 2 + 3, 256, 0, stream>>>(
      x, w1, b1, perm, gn1w, gn1b, c2w, c2b, gn2w, gn2b, c3w, c3b,
      E, swr, fc1w, fc2w, wTbuf, Bfb, W1fb, W2fb, out);
  dim3 g3(NB / 64, NFOR);
  k3_mfma<<<g3, 256, 0, stream>>>(wTbuf, swr, Bfb, W1fb, W2fb,
                                  ln1w, ln1b, fc1b, ln2w, ln2b, fc2b, out);
}